// Round 13
// baseline (46.755 us; speedup 1.0000x reference)
//
#include <hip/hip_runtime.h>
#include <math.h>

#define SIG 512
#define NA 45
#define DD 725          // DIAG
#define PB 106          // PAD_BEFORE
#define HALFF 362.0f    // 0.5*(DD-1); (2/724)*362 == 1 exactly
#define PI_D 3.14159265358979323846

// Strip radon: ONE WAVE owns (b, a, 32-wide d-strip, yi-half). It walks
// <=12 sub-windows (32 yi each), staging the same <=50x47 footprint as the
// proven tile kernel (10.24 KB LDS -> 15 blocks/CU), accumulating in
// REGISTERS (no atomics, no z-init), and ends with ONE plain store
// z_plane[h] = acc - y/2. Two planes (one per yi-half) => every (b,a,d)
// cell written exactly once per plane; iradon sums planes. This removes
// the prep kernel and one graph boundary (~5us of the measured ~15us
// inter-kernel machinery), all atomics, and all desc/bitmap traffic.
// RW2=52 non-pow2 (R9: pow2 = 32-way LDS conflicts; R11: padding loses).
#define TD2 32
#define NT2 23          // ceil(725/32)
#define NC42 13         // float4 granules per footprint row (52 floats)
#define RW2 52          // LDS row stride in floats — NOT a power of 2
#define RH2 47
#define NREG2 640       // 10 chunks x 64 granules
#define NSTRIP (2 * NA * NT2 * 2)     // 4140 one-wave blocks
#define NTILES2 (2 * NA * NT2 * NT2)  // fallback grid

// z planes: rows padded to 728; cells 0 and 726..727 are guards (handled
// by iradon's staging select — never written by strip radon).
#define ZSTR 728
#define ZPLANE (2 * NA * ZSTR)        // 65520 floats per plane
#define WS_NEED (2 * ZPLANE * 4)      // two planes
#define WS_FB (ZPLANE * 4)            // fallback: single plane

#define NZB 256                       // fallback prep blocks
#define SEGW2 32

__device__ __forceinline__ float cidx(int i) {
    return -1.0f + (float)i * (2.0f / 724.0f);
}

__device__ __forceinline__ void ref_trig(int a, float& ct, float& st) {
    float thf = (float)((double)(4 * a) * PI_D / 180.0);
    ct = (float)cos((double)thf);
    st = (float)sin((double)thf);
}

// ---------------- Kernel 1: strip radon (2 kernels total) ----------------
__global__ __launch_bounds__(64) void radon_strip(
    const float* __restrict__ x, const float* __restrict__ yin,
    float* __restrict__ z01) {
    __shared__ float4 reg4[NREG2];
    float* reg = (float*)reg4;
    int lane = threadIdx.x;

    int bid = blockIdx.x;
    int h = bid & 1; bid >>= 1;           // yi-half / z-plane index
    int td = bid % NT2; bid /= NT2;
    int a = bid % NA;
    int b = bid / NA;

    float ct, st;
    ref_trig(a, ct, st);
    float X0 = HALFF * (1.0f - ct - st);
    float Y0 = HALFF * (1.0f + st - ct);
    int d0 = td * TD2, dmax = min(d0 + TD2 - 1, DD - 1);
    const float lo = (float)(PB - 1), hi = (float)(PB + SIG);

    // Strip-wide yi live interval (same solve as the proven tile_geom,
    // with y-range [0, 724] and the strip's d-range).
    float Ax0 = fmaf(ct, (float)d0, X0), Ax1 = fmaf(ct, (float)dmax, X0);
    float Axlo = fminf(Ax0, Ax1), Axhi = fmaxf(Ax0, Ax1);
    float Ay0 = fmaf(-st, (float)d0, Y0), Ay1 = fmaf(-st, (float)dmax, Y0);
    float Aylo = fminf(Ay0, Ay1), Ayhi = fmaxf(Ay0, Ay1);
    float ylo = 0.0f, yhi = (float)(DD - 1);
    bool dead = false;
    if (st > 1e-6f) {
        ylo = fmaxf(ylo, (lo - Axhi) / st - 1.0f);
        yhi = fminf(yhi, (hi - Axlo) / st + 1.0f);
    } else if (Axhi <= lo || Axlo >= hi) { dead = true; }
    if (ct > 1e-6f) {
        ylo = fmaxf(ylo, (lo - Ayhi) / ct - 1.0f);
        yhi = fminf(yhi, (hi - Aylo) / ct + 1.0f);
    } else if (ct < -1e-6f) {
        ylo = fmaxf(ylo, (hi - Aylo) / ct - 1.0f);
        yhi = fminf(yhi, (lo - Ayhi) / ct + 1.0f);
    } else if (Ayhi <= lo || Aylo >= hi) { dead = true; }
    int yclo = max(0, (int)ceilf(ylo));
    int ychi = min(DD - 1, (int)floorf(yhi));
    int hs = 0, he = -1;
    if (!dead && ychi >= yclo) {          // this half's yi sub-range
        int n = ychi - yclo + 1;
        hs = yclo + ((n * h) >> 1);
        he = yclo + ((n * (h + 1)) >> 1) - 1;
    }

    int dl = lane & 31;
    int half = lane >> 5;
    int dAbs = d0 + dl;
    float acc = 0.0f;

    for (int k0 = hs; k0 <= he; k0 += 32) {
        int k1 = min(k0 + 31, he);
        float k0f = (float)k0, k1f = (float)k1;
        // d-clip for yi in [k0,k1] (tile_geom's d-interval solve)
        float dloF = (float)d0, dhiF = (float)dmax;
        if (ct > 1e-6f) {
            dloF = fmaxf(dloF, (lo - st * k1f - X0) / ct - 1.0f);
            dhiF = fminf(dhiF, (hi - st * k0f - X0) / ct + 1.0f);
        } else if (ct < -1e-6f) {
            dloF = fmaxf(dloF, (hi - st * k0f - X0) / ct - 1.0f);
            dhiF = fminf(dhiF, (lo - st * k1f - X0) / ct + 1.0f);
        }
        if (st > 1e-6f) {
            float yl2 = (ct >= 0.0f) ? k0f : k1f;
            float yh2 = (ct >= 0.0f) ? k1f : k0f;
            dloF = fmaxf(dloF, (Y0 + ct * yl2 - hi) / st - 1.0f);
            dhiF = fminf(dhiF, (Y0 + ct * yh2 - lo) / st + 1.0f);
        }
        int dclo = max(d0, (int)ceilf(dloF));
        int dchi = min(dmax, (int)floorf(dhiF));
        if (dchi < dclo) continue;        // window contributes nothing

        // bbox from clipped corners (same margins as tile_geom)
        float pxmin = 1e30f, pxmax = -1e30f, pymin = 1e30f, pymax = -1e30f;
        for (int ci = 0; ci < 4; ++ci) {
            float df = (float)((ci & 1) ? dchi : dclo);
            float yf = (ci & 2) ? k1f : k0f;
            float px_ = fmaf(st, yf, fmaf(ct, df, X0));
            float py_ = fmaf(ct, yf, fmaf(-st, df, Y0));
            pxmin = fminf(pxmin, px_); pxmax = fmaxf(pxmax, px_);
            pymin = fminf(pymin, py_); pymax = fmaxf(pymax, py_);
        }
        int cx0 = (int)floorf(pxmin) - 1;
        int ry0 = (int)floorf(pymin) - 1;
        int ry1 = (int)floorf(pymax) + 2;
        int cx0a = PB + (((cx0 - PB) >> 2) << 2);   // 4-col aligned
        int gcb = cx0a - PB;
        int grb = ry0 - PB;
        int nrows = min(ry1 - ry0 + 1, RH2);
        int nch = (nrows * NC42 + 63) >> 6;         // <= 10

        __syncthreads();   // prior window's LDS fully consumed before restage

        // conservative interior test (rmax <= 49 for nch <= 10)
        if ((grb >= 0) & (grb + 49 < SIG) & (gcb >= 0) & (gcb + 52 <= SIG)) {
            int r0 = (lane * 5) >> 6;               // == lane/13 for 0..63
            int c0 = lane - r0 * NC42;
            const float* src = x + (b << 18) + ((grb + r0) << 9) + gcb + (c0 << 2);
            for (int ch = 0; ch < nch; ++ch) {
                __builtin_amdgcn_global_load_lds(
                    (const __attribute__((address_space(1))) void*)src,
                    (__attribute__((address_space(3))) void*)(reg4 + (ch << 6)),
                    16, 0, 0);
                bool cy = (c0 != 0);
                src += cy ? (5 * SIG - 4) : (4 * SIG + 48);
                c0 = cy ? (c0 - 1) : (NC42 - 1);
            }
        } else {
            // border: zero-fill footprint, then masked loads (exec-masked
            // global_load_lds lanes simply don't write their LDS slot)
            float4 zv = {0.0f, 0.0f, 0.0f, 0.0f};
            for (int i = lane; i < (nch << 6); i += 64) reg4[i] = zv;
            asm volatile("s_waitcnt lgkmcnt(0)" ::: "memory");  // zeros land first
            for (int ch = 0; ch < nch; ++ch) {
                int vi = (ch << 6) + lane;
                int r = vi / NC42;                  // compile-time magic div
                int c = vi - r * NC42;
                int gr = grb + r;
                int gc = gcb + (c << 2);
                if (((unsigned)gr < SIG) & ((unsigned)gc < SIG)) {
                    const float* src = x + (b << 18) + (gr << 9) + gc;
                    __builtin_amdgcn_global_load_lds(
                        (const __attribute__((address_space(1))) void*)src,
                        (__attribute__((address_space(3))) void*)(reg4 + (ch << 6)),
                        16, 0, 0);
                }
            }
        }
        __syncthreads();                            // vmcnt fence (1 wave)

        // sample window: lanes = 32 d x 2 yi-sub-halves
        int wn = k1 - k0 + 1;
        int sq = k0 + ((wn * half) >> 1);
        int eq = k0 + ((wn * (half + 1)) >> 1) - 1;
        float lf = (float)min(max(dAbs, dclo), dchi);
        float pxb = X0 - (float)cx0a;
        float pyb = Y0 - (float)ry0;
        float px = fmaf(st, (float)sq, fmaf(ct, lf, pxb));
        float py = fmaf(ct, (float)sq, fmaf(-st, lf, pyb));
        float psum = 0.0f;
#pragma unroll 4
        for (int k = sq; k <= eq; ++k) {
            float fx = floorf(px), fy = floorf(py);
            float wx = px - fx, wy = py - fy;
            int addr = (int)fmaf(fy, (float)RW2, fx);
            float v00 = reg[addr],       v10 = reg[addr + 1];
            float v01 = reg[addr + RW2], v11 = reg[addr + RW2 + 1];
            float top = fmaf(wx, v10 - v00, v00);
            float bot = fmaf(wx, v11 - v01, v01);
            psum = fmaf(wy, bot - top, psum + top);
            px += st; py += ct;
        }
        acc += (dAbs >= dclo && dAbs <= dchi) ? psum : 0.0f;
    }

    acc += __shfl_xor(acc, 32);                     // join yi-sub-halves
    if (half == 0 && dAbs < DD) {                   // one plain store per cell
        float yv = yin[(b * DD + dAbs) * NA + a];
        z01[h * ZPLANE + (b * NA + a) * ZSTR + 1 + dAbs] =
            acc - 0.5f * yv;                        // z0+z1 = radon - y
    }
}

// ---------------- Kernel 2: backprojection (plane-summing) ----------------
// 16x16 px tiles, 2048 blocks (8/CU). Trig inline (no tbl). Staging sums
// the two z planes with a guard-cell select (cells outside [1,725] -> 0).
template <int TWO>
__global__ __launch_bounds__(256) void iradon16(const float* __restrict__ z0,
                                                const float* __restrict__ z1,
                                                float* __restrict__ out) {
    __shared__ float s_sc[NA], s_st2[NA];
    __shared__ int s_lo[NA];
    __shared__ float s_B[NA * 16];
    __shared__ float s_seg[NA * SEGW2];

    int t = threadIdx.x;
    int b = blockIdx.x >> 10;
    int tb = blockIdx.x & 1023;
    int i0 = (tb >> 5) << 4;
    int j0 = (tb & 31) << 4;

    if (t < NA) {
        float ct, st;
        ref_trig(t, ct, st);
        float sc = ct * HALFF;
        float st2 = -st * HALFF;
        float cxl = cidx(j0 + PB), cxh = cidx(j0 + 15 + PB);
        float cyl = cidx(i0 + PB), cyh = cidx(i0 + 15 + PB);
        float a00 = fmaf(sc, cxl, fmaf(st2, cyl, 363.0f));
        float a01 = fmaf(sc, cxl, fmaf(st2, cyh, 363.0f));
        float a10 = fmaf(sc, cxh, fmaf(st2, cyl, 363.0f));
        float a11 = fmaf(sc, cxh, fmaf(st2, cyh, 363.0f));
        float mn = fminf(fminf(a00, a01), fminf(a10, a11));
        int lo = (int)floorf(mn) - 1;
        lo = min(max(lo, 0), ZSTR - 1 - SEGW2);
        s_sc[t] = sc; s_st2[t] = st2; s_lo[t] = lo;
    }
    __syncthreads();

    for (int s = t; s < NA * 16; s += 256) {
        int a = s >> 4, ii = s & 15;
        s_B[s] = fmaf(s_st2[a], cidx(i0 + ii + PB), 363.0f - (float)s_lo[a]);
    }
    // Stage z segments: plane sum + guard select (cells 0, 726, 727 -> 0)
    int zb = b * NA * ZSTR;
    for (int s = t; s < NA * SEGW2; s += 256) {
        int a = s >> 5, idx = s & 31;
        int c = s_lo[a] + idx;
        float v = 0.0f;
        if (c >= 1 && c <= DD) {
            int off = zb + a * ZSTR + c;
            v = z0[off];
            if (TWO) v += z1[off];
        }
        s_seg[s] = v;
    }
    __syncthreads();

    float cxv = cidx(j0 + (t & 15) + PB);
    int r0 = t >> 4;
    float acc = 0.f;
    for (int a = 0; a < NA; ++a) {
        float af = fmaf(s_sc[a], cxv, s_B[(a << 4) + r0]);
        float fl = floorf(af);
        float wt = af - fl;
        int ia = (int)fl;                         // af in [1.0, 28.5]
        const float* sp = s_seg + (a << 5) + ia;
        float v0 = sp[0], v1 = sp[1];             // ds_read2_b32
        acc = fmaf(wt, v1 - v0, acc + v0);
    }
    const float sfin = (float)(PI_D / (2.0 * NA));
    out[(b << 18) + ((i0 + r0) << 9) + j0 + (t & 15)] = acc * sfin;
}

// ---------------- Fallback path (small workspace): 3 kernels ----------------
__global__ void prep_fb(const float* __restrict__ yin, float* __restrict__ z,
                        float* __restrict__ zpage) {
    int i = blockIdx.x * blockDim.x + threadIdx.x;
    if (i < 256) zpage[i] = 0.0f;
    if (i >= ZPLANE) return;
    int r = i / ZSTR;
    int c = i - r * ZSTR;
    float v = 0.0f;
    if (c >= 1 && c <= DD) {
        int d = c - 1;
        int a = r % NA;
        int b = r / NA;
        v = -yin[(b * DD + d) * NA + a];
    }
    z[i] = v;
}

__global__ __launch_bounds__(64) void radon_fb(const float* __restrict__ x,
                                               const float* __restrict__ zpage,
                                               float* __restrict__ z) {
    __shared__ float4 reg4[NREG2];
    float* reg = (float*)reg4;
    int lane = threadIdx.x;
    int tile = blockIdx.x;
    int td = tile % NT2; int rest = tile / NT2;
    int ty = rest % NT2; rest /= NT2;
    int a = rest % NA;
    int b = rest / NA;
    float ct, st;
    ref_trig(a, ct, st);
    float X0 = HALFF * (1.0f - ct - st);
    float Y0 = HALFF * (1.0f + st - ct);
    int d0 = td * TD2, dmax = min(d0 + TD2 - 1, DD - 1);
    int y0 = ty * TD2, ymax = min(y0 + TD2 - 1, DD - 1);
    const float lo = (float)(PB - 1), hi = (float)(PB + SIG);
    float Ax0 = fmaf(ct, (float)d0, X0), Ax1 = fmaf(ct, (float)dmax, X0);
    float Axlo = fminf(Ax0, Ax1), Axhi = fmaxf(Ax0, Ax1);
    float Ay0 = fmaf(-st, (float)d0, Y0), Ay1 = fmaf(-st, (float)dmax, Y0);
    float Aylo = fminf(Ay0, Ay1), Ayhi = fmaxf(Ay0, Ay1);
    float ylo = (float)y0, yhi = (float)ymax;
    if (st > 1e-6f) {
        ylo = fmaxf(ylo, (lo - Axhi) / st - 1.0f);
        yhi = fminf(yhi, (hi - Axlo) / st + 1.0f);
    } else if (Axhi <= lo || Axlo >= hi) { return; }
    if (ct > 1e-6f) {
        ylo = fmaxf(ylo, (lo - Ayhi) / ct - 1.0f);
        yhi = fminf(yhi, (hi - Aylo) / ct + 1.0f);
    } else if (ct < -1e-6f) {
        ylo = fmaxf(ylo, (hi - Aylo) / ct - 1.0f);
        yhi = fminf(yhi, (lo - Ayhi) / ct + 1.0f);
    } else if (Ayhi <= lo || Aylo >= hi) { return; }
    int yclo = max(y0, (int)ceilf(ylo));
    int ychi = min(ymax, (int)floorf(yhi));
    if (ychi < yclo) return;
    float yclof = (float)yclo, ychif = (float)ychi;
    float dloF = (float)d0, dhiF = (float)dmax;
    if (ct > 1e-6f) {
        dloF = fmaxf(dloF, (lo - st * ychif - X0) / ct - 1.0f);
        dhiF = fminf(dhiF, (hi - st * yclof - X0) / ct + 1.0f);
    } else if (ct < -1e-6f) {
        dloF = fmaxf(dloF, (hi - st * yclof - X0) / ct - 1.0f);
        dhiF = fminf(dhiF, (lo - st * ychif - X0) / ct + 1.0f);
    }
    if (st > 1e-6f) {
        float yl2 = (ct >= 0.0f) ? yclof : ychif;
        float yh2 = (ct >= 0.0f) ? ychif : yclof;
        dloF = fmaxf(dloF, (Y0 + ct * yl2 - hi) / st - 1.0f);
        dhiF = fminf(dhiF, (Y0 + ct * yh2 - lo) / st + 1.0f);
    }
    int dclo = max(d0, (int)ceilf(dloF));
    int dchi = min(dmax, (int)floorf(dhiF));
    if (dchi < dclo) return;
    float pxmin = 1e30f, pxmax = -1e30f, pymin = 1e30f, pymax = -1e30f;
    for (int ci = 0; ci < 4; ++ci) {
        float df = (float)((ci & 1) ? dchi : dclo);
        float yf = (float)((ci & 2) ? ychi : yclo);
        float px = fmaf(st, yf, fmaf(ct, df, X0));
        float py = fmaf(ct, yf, fmaf(-st, df, Y0));
        pxmin = fminf(pxmin, px); pxmax = fmaxf(pxmax, px);
        pymin = fminf(pymin, py); pymax = fmaxf(pymax, py);
    }
    int cx0 = (int)floorf(pxmin) - 1;
    int ry0 = (int)floorf(pymin) - 1;
    int ry1 = (int)floorf(pymax) + 2;
    int cx0a = PB + (((cx0 - PB) >> 2) << 2);
    int gcb = cx0a - PB;
    int grb = ry0 - PB;
    int nrows = min(ry1 - ry0 + 1, RH2);
    int nch = (nrows * NC42 + 63) >> 6;
    for (int ch = 0; ch < nch; ++ch) {
        int vi = (ch << 6) + lane;
        int r = vi / NC42;
        int c = vi - r * NC42;
        int gr = grb + r;
        int gc = gcb + (c << 2);
        bool valid = ((unsigned)gr < SIG) & ((unsigned)gc < SIG);
        const float* src = valid ? (x + (b << 18) + (gr << 9) + gc) : zpage;
        __builtin_amdgcn_global_load_lds(
            (const __attribute__((address_space(1))) void*)src,
            (__attribute__((address_space(3))) void*)(reg4 + (ch << 6)),
            16, 0, 0);
    }
    __syncthreads();
    int half = lane >> 5;
    int dl = lane & 31;
    int n = ychi - yclo + 1;
    int sq = yclo + ((n * half) >> 1);
    int eq = yclo + ((n * (half + 1)) >> 1) - 1;
    int dAbs = d0 + dl;
    float lf = (float)min(max(dAbs, dclo), dchi);
    float pxb = X0 - (float)cx0a;
    float pyb = Y0 - (float)ry0;
    float px = fmaf(st, (float)sq, fmaf(ct, lf, pxb));
    float py = fmaf(ct, (float)sq, fmaf(-st, lf, pyb));
    float sum = 0.0f;
#pragma unroll 4
    for (int k = sq; k <= eq; ++k) {
        float fx = floorf(px), fy = floorf(py);
        float wx = px - fx, wy = py - fy;
        int addr = (int)fmaf(fy, (float)RW2, fx);
        float v00 = reg[addr],       v10 = reg[addr + 1];
        float v01 = reg[addr + RW2], v11 = reg[addr + RW2 + 1];
        float top = fmaf(wx, v10 - v00, v00);
        float bot = fmaf(wx, v11 - v01, v01);
        sum = fmaf(wy, bot - top, sum + top);
        px += st; py += ct;
    }
    sum += __shfl_xor(sum, 32);
    if (half == 0 && dAbs >= dclo && dAbs <= dchi) {
        atomicAdd(&z[(b * NA + a) * ZSTR + 1 + dAbs], sum);
    }
}

extern "C" void kernel_launch(void* const* d_in, const int* in_sizes, int n_in,
                              void* d_out, int out_size, void* d_ws, size_t ws_size,
                              hipStream_t stream) {
    const float* x = (const float*)d_in[0];     // (2,1,512,512)
    const float* yin = (const float*)d_in[1];   // (2,1,725,45)
    float* out = (float*)d_out;                 // (2,1,512,512)
    float* z0 = (float*)d_ws;
    float* z1 = z0 + ZPLANE;

    if (ws_size >= (size_t)WS_NEED) {
        radon_strip<<<NSTRIP, 64, 0, stream>>>(x, yin, z0);
        iradon16<1><<<2048, 256, 0, stream>>>(z0, z1, out);
    } else {
        float* zpage = out;                     // zeros; iradon overwrites
        prep_fb<<<NZB, 256, 0, stream>>>(yin, z0, zpage);
        radon_fb<<<NTILES2, 64, 0, stream>>>(x, zpage, z0);
        iradon16<0><<<2048, 256, 0, stream>>>(z0, z0, out);
    }
}

// Round 14
// 40.425 us; speedup vs baseline: 1.1566x; 1.1566x over previous
//
#include <hip/hip_runtime.h>
#include <math.h>

#define SIG 512
#define NA 45
#define DD 725          // DIAG
#define PB 106          // PAD_BEFORE
#define HALFF 362.0f    // 0.5*(DD-1); (2/724)*362 == 1 exactly
#define PI_D 3.14159265358979323846

// 32x32 (d x yi) tiles, ONE WAVE (64 thr) per tile; footprint <= 50x47.
// 10.24 KB LDS -> 15 blocks/CU. RW2=52 (stride % 32 = 20) is deliberate:
// R9 proved RW2=64 (pow2) -> up-to-32-way LDS conflicts (+11us); R11
// proved RW2=60 padding costs more in staging+occupancy than it saves
// (+5us); R13 proved strip-fusion (fewer, serial waves) costs +6us.
// Radon runs at ~88% of its VALU-issue floor (R5: VALUBusy 101%).
#define TD2 32
#define TY2 32
#define NT2 23          // ceil(725/32)
#define NC42 13         // float4 cols staged (52 floats >= 50 needed)
#define RW2 52          // region row stride in floats — NOT a power of 2
#define RH2 47
#define NREG2 640       // 10 chunks x 64 lanes of float4 (>= 47*13=611)
#define NTILES2 (2 * NA * NT2 * NT2)  // 47610
#define TGRP (NT2 * NT2)              // 529 tiles per (b,a) group

// z rows padded: stride 728, cell 0 and 726..727 are zero guards.
#define ZSTR 728
#define ZELEMS (2 * NA * ZSTR)        // 65520
#define TBLOFF ZELEMS                 // 90-float cos/sin table
#define DESCOFF 65616                 // 16B-aligned float index for desc
#define DESCI 12                      // ints per tile descriptor (48B)
#define BMOFF (DESCOFF + NTILES2 * DESCI)      // live-tile bitmap (dwords)
#define BMWORDS 1492                            // ceil(47610/32)=1488 + pad
#define WS_NEED ((BMOFF + BMWORDS) * 4)
#define WS_TBL ((TBLOFF + 2 * NA) * 4)

#define NZB 256                       // prep blocks for z-init
#define NSB 186                       // prep blocks for desc (47610/256)

// iradon: 16x16 px tiles -> 2048 blocks (8/CU). VALU-bound (R7: 97%).
#define SEGW2 32

__device__ __forceinline__ float cidx(int i) {
    return -1.0f + (float)i * (2.0f / 724.0f);
}

__device__ __forceinline__ void ref_trig(int a, float& ct, float& st) {
    float thf = (float)((double)(4 * a) * PI_D / 180.0);
    ct = (float)cos((double)thf);
    st = (float)sin((double)thf);
}

// Tile geometry with BOTH-axis integer clipping. Returns false if dead.
// dlohi = (dclo-d0) | (dchi-d0)<<8 ; kske = (yclo-y0) | (ychi-y0)<<8.
__device__ __forceinline__ bool tile_geom(
    int a, int b, int td, int ty, float ct, float st,
    int& dlohi, int& gcb, int& grb, int& nrows, int& kske, int& y0i,
    int& zbase, int& boff, float& pxbase, float& pybase) {
    float X0 = HALFF * (1.0f - ct - st);
    float Y0 = HALFF * (1.0f + st - ct);
    int d0 = td * TD2, dmax = min(d0 + TD2 - 1, DD - 1);
    int y0 = ty * TY2, ymax = min(y0 + TY2 - 1, DD - 1);
    const float lo = (float)(PB - 1), hi = (float)(PB + SIG);

    float Ax0 = fmaf(ct, (float)d0, X0), Ax1 = fmaf(ct, (float)dmax, X0);
    float Axlo = fminf(Ax0, Ax1), Axhi = fmaxf(Ax0, Ax1);
    float Ay0 = fmaf(-st, (float)d0, Y0), Ay1 = fmaf(-st, (float)dmax, Y0);
    float Aylo = fminf(Ay0, Ay1), Ayhi = fmaxf(Ay0, Ay1);
    float ylo = (float)y0, yhi = (float)ymax;
    if (st > 1e-6f) {
        ylo = fmaxf(ylo, (lo - Axhi) / st - 1.0f);
        yhi = fminf(yhi, (hi - Axlo) / st + 1.0f);
    } else if (Axhi <= lo || Axlo >= hi) { return false; }
    if (ct > 1e-6f) {
        ylo = fmaxf(ylo, (lo - Ayhi) / ct - 1.0f);
        yhi = fminf(yhi, (hi - Aylo) / ct + 1.0f);
    } else if (ct < -1e-6f) {
        ylo = fmaxf(ylo, (hi - Aylo) / ct - 1.0f);
        yhi = fminf(yhi, (lo - Ayhi) / ct + 1.0f);
    } else if (Ayhi <= lo || Aylo >= hi) { return false; }
    int yclo = max(y0, (int)ceilf(ylo));
    int ychi = min(ymax, (int)floorf(yhi));
    if (ychi < yclo) return false;
    float yclof = (float)yclo, ychif = (float)ychi;

    float dloF = (float)d0, dhiF = (float)dmax;
    if (ct > 1e-6f) {
        dloF = fmaxf(dloF, (lo - st * ychif - X0) / ct - 1.0f);
        dhiF = fminf(dhiF, (hi - st * yclof - X0) / ct + 1.0f);
    } else if (ct < -1e-6f) {
        dloF = fmaxf(dloF, (hi - st * yclof - X0) / ct - 1.0f);
        dhiF = fminf(dhiF, (lo - st * ychif - X0) / ct + 1.0f);
    }
    if (st > 1e-6f) {
        float yl2 = (ct >= 0.0f) ? yclof : ychif;
        float yh2 = (ct >= 0.0f) ? ychif : yclof;
        dloF = fmaxf(dloF, (Y0 + ct * yl2 - hi) / st - 1.0f);
        dhiF = fminf(dhiF, (Y0 + ct * yh2 - lo) / st + 1.0f);
    }
    int dclo = max(d0, (int)ceilf(dloF));
    int dchi = min(dmax, (int)floorf(dhiF));
    if (dchi < dclo) return false;

    float pxmin = 1e30f, pxmax = -1e30f, pymin = 1e30f, pymax = -1e30f;
    for (int ci = 0; ci < 4; ++ci) {
        float df = (float)((ci & 1) ? dchi : dclo);
        float yf = (float)((ci & 2) ? ychi : yclo);
        float px = fmaf(st, yf, fmaf(ct, df, X0));
        float py = fmaf(ct, yf, fmaf(-st, df, Y0));
        pxmin = fminf(pxmin, px); pxmax = fmaxf(pxmax, px);
        pymin = fminf(pymin, py); pymax = fmaxf(pymax, py);
    }
    int cx0 = (int)floorf(pxmin) - 1;
    int cx1 = (int)floorf(pxmax) + 2;
    int ry0 = (int)floorf(pymin) - 1;
    int ry1 = (int)floorf(pymax) + 2;
    if (cx1 < PB || cx0 >= PB + SIG || ry1 < PB || ry0 >= PB + SIG) return false;

    int cx0a = PB + (((cx0 - PB) >> 2) << 2);   // 4-col aligned
    nrows = min(ry1 - ry0 + 1, RH2);
    gcb = cx0a - PB;
    grb = ry0 - PB;
    dlohi = (dclo - d0) | ((dchi - d0) << 8);
    kske = (yclo - y0) | ((ychi - y0) << 8);
    y0i = y0;
    zbase = (b * NA + a) * ZSTR + 1 + d0;
    boff = b * SIG * SIG;
    pxbase = fmaf(ct, (float)d0, X0) - (float)cx0a;
    pybase = fmaf(-st, (float)d0, Y0) - (float)ry0;
    return true;
}

// Kernel 0 (fused prep): blocks [0,NZB) init z rows (+trig tbl, zpage in
// block 0); blocks [NZB,NZB+NSB) build tile descriptors + live bitmap.
// Interior flag (whole staged footprint in-image) packed into dlohi bit 16.
template <int MODE>   // 2 = z+tbl+desc+bitmap, 1 = z+tbl, 0 = z only
__global__ void prep(const float* __restrict__ yin, float* __restrict__ z,
                     float* __restrict__ tbl, float* __restrict__ zpage,
                     int* __restrict__ desc, unsigned* __restrict__ bmap) {
    __shared__ float s_trig[4];
    __shared__ int s_ag[2];
    if (blockIdx.x < NZB) {
        int i = blockIdx.x * blockDim.x + threadIdx.x;
        if (i < 256) zpage[i] = 0.0f;
        if (MODE >= 1 && blockIdx.x == 0 && threadIdx.x < NA) {
            float ct, st;
            ref_trig(threadIdx.x, ct, st);
            tbl[2 * threadIdx.x] = ct;
            tbl[2 * threadIdx.x + 1] = st;
        }
        if (i >= ZELEMS) return;
        int r = i / ZSTR;                 // (b*NA + a)
        int c = i - r * ZSTR;
        float v = 0.0f;
        if (c >= 1 && c <= DD) {
            int d = c - 1;
            int a = r % NA;
            int b = r / NA;
            v = -yin[(b * DD + d) * NA + a];
        }
        z[i] = v;
        return;
    }
    if (MODE < 2) return;
    int base = (blockIdx.x - NZB) * blockDim.x;
    if (threadIdx.x < 2) {
        int tl = min(base + (int)threadIdx.x * 255, NTILES2 - 1);
        int ag = tl / TGRP;               // b*NA + a
        s_ag[threadIdx.x] = ag;
        float ct, st;
        ref_trig(ag % NA, ct, st);
        s_trig[2 * threadIdx.x] = ct;
        s_trig[2 * threadIdx.x + 1] = st;
    }
    __syncthreads();
    int tile = base + threadIdx.x;
    bool live = false;
    int dlohi, gcb, grb, nrows, kske, y0i, zbase, boff;
    float pxbase, pybase;
    float ct = 0.0f, st = 0.0f;
    if (tile < NTILES2) {
        int td = tile % NT2; int rest = tile / NT2;
        int ty = rest % NT2;
        int ag = rest / NT2;              // b*NA + a
        int a = ag % NA;
        int b = ag / NA;
        int sel = (ag == s_ag[0]) ? 0 : 2;
        ct = s_trig[sel]; st = s_trig[sel + 1];
        live = tile_geom(a, b, td, ty, ct, st, dlohi, gcb, grb, nrows, kske,
                         y0i, zbase, boff, pxbase, pybase);
    }
    unsigned long long m = __ballot(live);
    if ((threadIdx.x & 63) == 0) {        // lane0 tile is 64-aligned
        int w = tile >> 5;
        bmap[w] = (unsigned)m;
        bmap[w + 1] = (unsigned)(m >> 32);
    }
    if (!live) return;
    // interior flag: every staged (r,c) in-image incl. the r-overshoot of
    // the last chunk (rmax = (nch*64-1)/13) and the 16B col reach (+51).
    {
        int nch = (nrows * NC42 + 63) >> 6;
        int rmax = (nch * 64 - 1) / NC42;
        if (grb >= 0 && grb + rmax < SIG && gcb >= 0 && gcb + 52 <= SIG)
            dlohi |= (1 << 16);
    }
    int* dp = desc + tile * DESCI;
    float* fp = (float*)dp;
    dp[0] = dlohi; dp[1] = gcb; dp[2] = grb; dp[3] = nrows;
    dp[4] = kske; fp[5] = pxbase; fp[6] = pybase;
    dp[7] = y0i; dp[8] = zbase; dp[9] = boff;
    fp[10] = ct; fp[11] = st;             // trig embedded: no tbl load in radon
}

// One-wave tile body (R6-proven form). Staging: interior tiles walk a
// 2-case incremental 64-bit src pointer; border tiles full clamped path.
// Sample: incremental px/py, floorf/fmaf addressing (R8 proved hand-asm
// fract re-spelling regresses codegen — do not touch).
__device__ __forceinline__ void process_tile32(
    const float* __restrict__ img, const float* __restrict__ zpage,
    float ct, float st,
    int dlohi, int gcb, int grb, int nrows, int kske, int y0i, int zbase,
    float pxbase, float pybase,
    float4* reg4, float* __restrict__ z) {
    float* reg = (float*)reg4;
    int lane = threadIdx.x;                      // 0..63

    int nch = (nrows * NC42 + 63) >> 6;          // <= 10
    if (dlohi & (1 << 16)) {
        int r0 = (lane * 5) >> 6;                // == lane/13 for 0..63
        int c0 = lane - r0 * NC42;
        const float* src = img + ((grb + r0) << 9) + gcb + (c0 << 2);
        for (int ch = 0; ch < nch; ++ch) {
            __builtin_amdgcn_global_load_lds(
                (const __attribute__((address_space(1))) void*)src,
                (__attribute__((address_space(3))) void*)(reg4 + (ch << 6)),
                16, 0, 0);
            bool cy = (c0 != 0);
            src += cy ? (5 * SIG - 4) : (4 * SIG + 48);
            c0 = cy ? (c0 - 1) : (NC42 - 1);
        }
    } else {
        for (int ch = 0; ch < nch; ++ch) {
            int vi = (ch << 6) + lane;
            int r = vi / NC42;                   // compile-time magic div
            int c = vi - r * NC42;
            int gr = grb + r;
            int gc = gcb + (c << 2);             // multiple of 4
            bool valid = ((unsigned)gr < SIG) & ((unsigned)gc < SIG);
            const float* src = valid ? (img + (gr << 9) + gc) : zpage;
            __builtin_amdgcn_global_load_lds(
                (const __attribute__((address_space(1))) void*)src,
                (__attribute__((address_space(3))) void*)(reg4 + (ch << 6)),
                16, 0, 0);
        }
    }
    __syncthreads();                             // 1 wave: vmcnt fence

    int half = lane >> 5;
    int dl = lane & 31;
    int ksb = kske & 255, keb = kske >> 8;       // keb >= ksb guaranteed
    int dlo = dlohi & 255, dhi = (dlohi >> 8) & 255;
    int n = keb - ksb + 1;
    int sq = ksb + ((n * half) >> 1);
    int eq = ksb + ((n * (half + 1)) >> 1) - 1;

    float lf = (float)min(max(dl, dlo), dhi);    // clamp into live d-range
    float pxd = fmaf(ct, lf, pxbase);
    float pyd = fmaf(-st, lf, pybase);
    float yif = (float)(y0i + sq);
    float px = fmaf(st, yif, pxd);
    float py = fmaf(ct, yif, pyd);
    float sum = 0.0f;
#pragma unroll 4
    for (int k = sq; k <= eq; ++k) {
        float fx = floorf(px), fy = floorf(py);
        float wx = px - fx, wy = py - fy;
        int addr = (int)fmaf(fy, (float)RW2, fx);    // exact: < 2^24
        float v00 = reg[addr],       v10 = reg[addr + 1];
        float v01 = reg[addr + RW2], v11 = reg[addr + RW2 + 1];
        float top = fmaf(wx, v10 - v00, v00);
        float bot = fmaf(wx, v11 - v01, v01);
        sum = fmaf(wy, bot - top, sum + top);
        px += st; py += ct;                      // drift <= 16 ulp(50): ok
    }
    sum += __shfl_xor(sum, 32);                  // pair (dl, dl+32)
    if (half == 0 && dl >= dlo && dl <= dhi) {   // only live d-lanes emit
        atomicAdd(&z[zbase + dl], sum);
    }
}

// Kernel 1: radon, one wave per tile; scalar bitmap gate for dead tiles.
__global__ __launch_bounds__(64) void radon32f(const float* __restrict__ x,
                                               const float* __restrict__ zpage,
                                               const int* __restrict__ desc,
                                               const unsigned* __restrict__ bmap,
                                               float* __restrict__ z) {
    __shared__ float4 reg4[NREG2];
    unsigned w = bmap[blockIdx.x >> 5];          // uniform -> s_load, K$-hot
    if (!((w >> (blockIdx.x & 31)) & 1u)) return;
    const int* dp = desc + blockIdx.x * DESCI;
    const float* fp = (const float*)dp;
    process_tile32(x + dp[9], zpage, fp[10], fp[11],
                   dp[0], dp[1], dp[2], dp[3], dp[4], dp[7], dp[8],
                   fp[5], fp[6], reg4, z);
}

// Fallback kernel 1: one 64-thread block per tile, geometry inline.
template <int TBL>
__global__ __launch_bounds__(64) void radon32(const float* __restrict__ x,
                                              const float* __restrict__ zpage,
                                              const float* __restrict__ tbl,
                                              float* __restrict__ z) {
    __shared__ float4 reg4[NREG2];
    int tile = blockIdx.x;
    int td = tile % NT2; int rest = tile / NT2;
    int ty = rest % NT2; rest /= NT2;
    int a = rest % NA;
    int b = rest / NA;
    float ct, st;
    if (TBL) { ct = tbl[2 * a]; st = tbl[2 * a + 1]; }
    else     { ref_trig(a, ct, st); }
    int dlohi, gcb, grb, nrows, kske, y0i, zbase, boff;
    float pxbase, pybase;
    if (!tile_geom(a, b, td, ty, ct, st, dlohi, gcb, grb, nrows, kske, y0i,
                   zbase, boff, pxbase, pybase)) return;
    process_tile32(x + boff, zpage, ct, st, dlohi, gcb, grb, nrows, kske,
                   y0i, zbase, pxbase, pybase, reg4, z);
}

// Kernel 2: tiled backprojection, 16x16 px tiles (2048 blocks -> 8/CU).
// Tap index clamp dropped (provably dead: af in [1.0, 28.5] — lo
// construction bounds tile t-spread <= 15(|ct|+|st|)*1.0003 <= 21.3).
template <int TBL>
__global__ __launch_bounds__(256) void iradon16(const float* __restrict__ z,
                                                const float* __restrict__ tbl,
                                                float* __restrict__ out) {
    __shared__ float s_sc[NA], s_st2[NA];
    __shared__ int s_lo[NA];
    __shared__ float s_B[NA * 16];
    __shared__ float s_seg[NA * SEGW2];

    int t = threadIdx.x;
    int b = blockIdx.x >> 10;
    int tb = blockIdx.x & 1023;
    int i0 = (tb >> 5) << 4;
    int j0 = (tb & 31) << 4;

    if (t < NA) {
        float ct, st;
        if (TBL) { ct = tbl[2 * t]; st = tbl[2 * t + 1]; }
        else     { ref_trig(t, ct, st); }
        float sc = ct * HALFF;
        float st2 = -st * HALFF;
        float cxl = cidx(j0 + PB), cxh = cidx(j0 + 15 + PB);
        float cyl = cidx(i0 + PB), cyh = cidx(i0 + 15 + PB);
        float a00 = fmaf(sc, cxl, fmaf(st2, cyl, 363.0f));
        float a01 = fmaf(sc, cxl, fmaf(st2, cyh, 363.0f));
        float a10 = fmaf(sc, cxh, fmaf(st2, cyl, 363.0f));
        float a11 = fmaf(sc, cxh, fmaf(st2, cyh, 363.0f));
        float mn = fminf(fminf(a00, a01), fminf(a10, a11));
        int lo = (int)floorf(mn) - 1;
        lo = min(max(lo, 0), ZSTR - 1 - SEGW2);  // keep lo..lo+31 in-row
        s_sc[t] = sc; s_st2[t] = st2; s_lo[t] = lo;
    }
    __syncthreads();

    // Row-base table: B[a][ii] = st2*cy(i0+ii) + (363 - lo)
    for (int s = t; s < NA * 16; s += 256) {
        int a = s >> 4, ii = s & 15;
        s_B[s] = fmaf(s_st2[a], cidx(i0 + ii + PB), 363.0f - (float)s_lo[a]);
    }
    // Stage z segments (L2 -> LDS, runs of 32)
    const float* zb = z + b * NA * ZSTR;
    for (int s = t; s < NA * SEGW2; s += 256) {
        int a = s >> 5, idx = s & 31;
        s_seg[s] = zb[a * ZSTR + s_lo[a] + idx];
    }
    __syncthreads();

    float cxv = cidx(j0 + (t & 15) + PB);
    int r0 = t >> 4;                              // 0..15
    float acc = 0.f;
    for (int a = 0; a < NA; ++a) {
        float af = fmaf(s_sc[a], cxv, s_B[(a << 4) + r0]);
        float fl = floorf(af);
        float wt = af - fl;
        int ia = (int)fl;                         // af in [1.0, 28.5]
        const float* sp = s_seg + (a << 5) + ia;
        float v0 = sp[0], v1 = sp[1];             // ds_read2_b32
        acc = fmaf(wt, v1 - v0, acc + v0);
    }
    const float sfin = (float)(PI_D / (2.0 * NA));
    out[(b << 18) + ((i0 + r0) << 9) + j0 + (t & 15)] = acc * sfin;
}

extern "C" void kernel_launch(void* const* d_in, const int* in_sizes, int n_in,
                              void* d_out, int out_size, void* d_ws, size_t ws_size,
                              hipStream_t stream) {
    const float* x = (const float*)d_in[0];     // (2,1,512,512)
    const float* yin = (const float*)d_in[1];   // (2,1,725,45)
    float* out = (float*)d_out;                 // (2,1,512,512)
    float* z = (float*)d_ws;                    // guard-padded (2,45,728)
    float* tbl = z + TBLOFF;
    int* desc = (int*)(z + DESCOFF);
    unsigned* bmap = (unsigned*)(z + BMOFF);
    float* zpage = out;                         // 256 zeros; iradon overwrites

    if (ws_size >= (size_t)WS_NEED) {
        prep<2><<<NZB + NSB, 256, 0, stream>>>(yin, z, tbl, zpage, desc, bmap);
        radon32f<<<NTILES2, 64, 0, stream>>>(x, zpage, desc, bmap, z);
        iradon16<1><<<2048, 256, 0, stream>>>(z, tbl, out);
    } else if (ws_size >= (size_t)WS_TBL) {
        prep<1><<<NZB, 256, 0, stream>>>(yin, z, tbl, zpage, nullptr, nullptr);
        radon32<1><<<NTILES2, 64, 0, stream>>>(x, zpage, tbl, z);
        iradon16<1><<<2048, 256, 0, stream>>>(z, tbl, out);
    } else {
        prep<0><<<NZB, 256, 0, stream>>>(yin, z, nullptr, zpage, nullptr, nullptr);
        radon32<0><<<NTILES2, 64, 0, stream>>>(x, zpage, nullptr, z);
        iradon16<0><<<2048, 256, 0, stream>>>(z, nullptr, out);
    }
}